// Round 11
// baseline (162.173 us; speedup 1.0000x reference)
//
#include <hip/hip_runtime.h>
#include <hip/hip_bf16.h>
#include <stdint.h>

// Problem constants (fixed by setup_inputs)
#define M_N  16384   // batch rows
#define K_C  2048    // centers
#define DIM  512     // feature dim
#define NCLS 10      // classes
#define NSL  16      // partial slices: 8 bn-chunks x 2 center-halves
#define BM   128     // batches per block
#define BN   256     // centers per block
#define BK   64

typedef unsigned short u16;
typedef float  f32x4  __attribute__((ext_vector_type(4)));
typedef __bf16 bf16x8 __attribute__((ext_vector_type(8)));

// ---- helpers -------------------------------------------------------------

__device__ __forceinline__ void async_ld16(const void* g, void* l) {
  // global -> LDS direct DMA, 16 B/lane; LDS dest must be linear in tid,
  // so the XOR swizzle is applied on the global SOURCE address.
  __builtin_amdgcn_global_load_lds(
      (const __attribute__((address_space(1))) void*)g,
      (__attribute__((address_space(3))) void*)l,
      16, 0, 0);
}

__device__ __forceinline__ u16 f2bf_rne(float f) {
  uint32_t u = __float_as_uint(f);
  u += 0x7FFFu + ((u >> 16) & 1u);
  return (u16)(u >> 16);
}

// ---- kernel 1: prep ------------------------------------------------------
// blocks [0, NPREP): 4 rows/block, one wave per row (coalesced i*64+lane).
// last 32 blocks: W fp32 [10][2048] -> PERMUTED bf16 [16][2048] matching the
// stage-2 register order (bn 256-chunk, half h, t, q, j).

#define NPREP ((M_N + K_C) / 4)   // 4608

__global__ __launch_bounds__(256) void prep(
    const float4* __restrict__ batches, const float4* __restrict__ centers,
    const float* __restrict__ W,
    ushort4* __restrict__ Abf, ushort4* __restrict__ Bbf,
    float* __restrict__ x2, float* __restrict__ c2, u16* __restrict__ Wperm) {
  int b = blockIdx.x, t = threadIdx.x;
  if (b < NPREP) {
    int lane = t & 63;
    int rp = b * 4 + (t >> 6);          // one wave per row
    const float4* src; ushort4* dst; float* sq; int row;
    if (rp < M_N) { src = batches; dst = Abf; sq = x2; row = rp; }
    else          { src = centers; dst = Bbf; sq = c2; row = rp - M_N; }
    float ss = 0.f;
#pragma unroll
    for (int i = 0; i < 2; ++i) {
      float4 v = src[(size_t)row * 128 + i * 64 + lane];
      ss += v.x * v.x + v.y * v.y + v.z * v.z + v.w * v.w;
      ushort4 o;
      o.x = f2bf_rne(v.x); o.y = f2bf_rne(v.y);
      o.z = f2bf_rne(v.z); o.w = f2bf_rne(v.w);
      dst[(size_t)row * 128 + i * 64 + lane] = o;
    }
    ss += __shfl_down(ss, 32);
    ss += __shfl_down(ss, 16);
    ss += __shfl_down(ss, 8);
    ss += __shfl_down(ss, 4);
    ss += __shfl_down(ss, 2);
    ss += __shfl_down(ss, 1);
    if (lane == 0) sq[row] = ss;
  } else {
    int wb = b - NPREP;                 // 32 blocks x 1024 elems
#pragma unroll
    for (int i = 0; i < 4; ++i) {
      int p = wb * 1024 + i * 256 + t;  // < 16*2048
      int cls = p >> 11, k = p & 2047;
      int bnn = k >> 8, rem = k & 255;
      int h = rem >> 7, rem2 = rem & 127;
      int tt = rem2 >> 5, qq = (rem2 >> 3) & 3, jj = rem2 & 7;
      int c = bnn * 256 + h * 128 + (2 * tt + (jj >> 2)) * 16 + qq * 4 + (jj & 3);
      Wperm[p] = (cls < NCLS) ? f2bf_rne(W[cls * K_C + c]) : (u16)0;
    }
  }
}

// ---- kernel 2: fused xc-GEMM -> radial -> MFMA (radial@Wperm^T) ----------
// grid = 1024 blocks (8 bn x 128 bm, XCD-swizzled), 256 thr = 4 waves.
// Block tile 128 batches x 256 centers; wave = 128 centers x 64 batches
// (F/B = 42.7 vs 64x64's 32 -- raises FLOP per LDS byte).
// ONLY centers are LDS-staged (32 KB, double-buffered, ONE barrier/iter);
// batch fragments come straight from global (L2-hot, 64 B segments).
// Each wave owns partial slice bn*2+h -- no cross-wave reduction.

__global__ __launch_bounds__(256, 2) void rbf_main(
    const u16* __restrict__ A,      // bf16 bits [M_N][DIM]  (batches)
    const u16* __restrict__ B,      // bf16 bits [K_C][DIM]  (centers)
    const float* __restrict__ x2,   // [M_N]
    const float* __restrict__ c2,   // [K_C]
    const float* __restrict__ beta, // [K_C]
    const u16* __restrict__ Wperm,  // bf16 bits [16][K_C] permuted
    float* __restrict__ partial) {  // [NSL][M_N][16]
  __shared__ u16 Bs[2][BN * BK];    // 64 KB double-buffered centers

  const int tid  = threadIdx.x;
  const int lane = tid & 63;
  const int wid  = tid >> 6;
  const int bid = blockIdx.x;
  const int g = bid >> 3, r8 = bid & 7;
  const int bm = r8 * 16 + (g & 15);   // XCD-local bm slice
  const int bn = g >> 4;               // 0..7
  const int row0 = bm * BM, col0 = bn * BN;
  const int wc2 = (wid & 1) * 128;     // wave center half
  const int wb2 = (wid >> 1) * 64;     // wave batch half
  const int cls = lane & 15, q = lane >> 4;
  const int fsw = cls & 7;             // frag swizzle key (frow == cls)

  f32x4 acc[8][4] = {};   // [mi centers][ni batches]

  // DMA source: thread t -> LDS slot (row 32i + (t>>3), slot t&7) holds
  // global chunk (t&7)^((t>>3)&7) of that row.
  const int srow = tid >> 3;
  const int schunk = (tid & 7) ^ (srow & 7);
  const u16* bG = B + (size_t)(col0 + srow) * DIM + schunk * 8;

  // batch row pointers (direct-global B-operand)
  const u16* aR[4];
#pragma unroll
  for (int ni = 0; ni < 4; ++ni)
    aR[ni] = A + (size_t)(row0 + wb2 + ni * 16 + cls) * DIM + q * 8;

#define FILL(buf, k0)                                                    \
  {                                                                      \
    _Pragma("unroll")                                                    \
    for (int i = 0; i < 8; ++i)                                          \
      async_ld16(bG + (k0) + i * 32 * DIM, &Bs[buf][i * 2048] + tid * 8);\
  }

  FILL(0, 0)
  for (int it = 0; it < 8; ++it) {
    __syncthreads();   // current buf DMA done + prev compute done
    if (it < 7) FILL((it + 1) & 1, (it + 1) * BK)
    const u16* bsb = Bs[it & 1];
    // hoist both kh's batch frags (independent global loads, deep in flight)
    bf16x8 bfr[2][4];
#pragma unroll
    for (int kh = 0; kh < 2; ++kh)
#pragma unroll
      for (int ni = 0; ni < 4; ++ni)
        bfr[kh][ni] = *(const bf16x8*)(aR[ni] + it * BK + kh * 32);
#pragma unroll
    for (int kh = 0; kh < 2; ++kh) {
      bf16x8 cf[8];
#pragma unroll
      for (int mi = 0; mi < 8; ++mi)
        cf[mi] = *(const bf16x8*)(bsb + (wc2 + mi * 16 + cls) * BK +
                                  (((kh << 2) | q) ^ fsw) * 8);
#pragma unroll
      for (int mi = 0; mi < 8; ++mi)
#pragma unroll
        for (int ni = 0; ni < 4; ++ni)
          acc[mi][ni] = __builtin_amdgcn_mfma_f32_16x16x32_bf16(
              cf[mi], bfr[kh][ni], acc[mi][ni], 0, 0, 0);
    }
  }

  // ---- epilogue: acc (xc) -> radial, in place, strip-by-strip ----
  // D layout: col(lane&15)=batch within ni-strip, row(q*4+r)=center.
  float x2v[4];
#pragma unroll
  for (int ni = 0; ni < 4; ++ni)
    x2v[ni] = x2[row0 + wb2 + ni * 16 + cls];
#pragma unroll
  for (int mi = 0; mi < 8; ++mi) {
    int base = col0 + wc2 + mi * 16 + q * 4;
    float4 cq = *(const float4*)(c2 + base);
    float4 bq = *(const float4*)(beta + base);
#pragma unroll
    for (int ni = 0; ni < 4; ++ni)
#pragma unroll
      for (int r = 0; r < 4; ++r) {
        float xc = acc[mi][ni][r];
        float d2 = fmaxf(x2v[ni] + cq[r] - 2.0f * xc, 0.0f);
        acc[mi][ni][r] = __expf(-bq[r] * sqrtf(d2));
      }
  }

  // ---- stage 2: acc2[64 x 16cls] = radial(128 centers) @ Wperm^T ----
  // Wperm matches register order: k=q*8+j <-> center (2t+(j>>2))*16+q*4+(j&3)
  const int h = wid & 1;
  f32x4 acc2[4] = {};
#pragma unroll
  for (int t = 0; t < 4; ++t) {
    bf16x8 wfr = *(const bf16x8*)(Wperm + (size_t)cls * K_C + col0 +
                                  h * 128 + t * 32 + q * 8);
#pragma unroll
    for (int ni = 0; ni < 4; ++ni) {
      union { u16 hh[8]; bf16x8 v; } pk;
#pragma unroll
      for (int r = 0; r < 4; ++r) {
        pk.hh[r]     = f2bf_rne(acc[2 * t][ni][r]);
        pk.hh[4 + r] = f2bf_rne(acc[2 * t + 1][ni][r]);
      }
      acc2[ni] = __builtin_amdgcn_mfma_f32_16x16x32_bf16(
          pk.v, wfr, acc2[ni], 0, 0, 0);
    }
  }

  // store: each wave owns slice bn*2+h; rows wb2..wb2+63; nt (read-once).
  const int slice = bn * 2 + h;
#pragma unroll
  for (int ni = 0; ni < 4; ++ni)
#pragma unroll
    for (int r = 0; r < 4; ++r) {
      int gr = row0 + wb2 + ni * 16 + q * 4 + r;
      __builtin_nontemporal_store(
          acc2[ni][r], &partial[((size_t)slice * M_N + gr) * 16 + cls]);
    }
}

// ---- kernel 3: out[i][:] = b + sum_s partial[s][i][:] --------------------
// 4 threads per row (float4 quads); 1 KB contiguous per wave per slice.

__global__ __launch_bounds__(256) void reduce_out(
    const float* __restrict__ partial, const float* __restrict__ b,
    float* __restrict__ out) {
  int t = threadIdx.x;
  int row = blockIdx.x * 64 + (t >> 2);
  int quad = t & 3;
  f32x4 v = {0.f, 0.f, 0.f, 0.f};
#pragma unroll
  for (int s = 0; s < NSL; ++s) {
    f32x4 p = __builtin_nontemporal_load(
        (const f32x4*)(partial + ((size_t)s * M_N + row) * 16 + quad * 4));
    v += p;
  }
  if (quad == 0) {
    float4 bq = *(const float4*)b;
    float* o = out + (size_t)row * NCLS;
    *(float2*)o       = {v.x + bq.x, v.y + bq.y};
    *(float2*)(o + 2) = {v.z + bq.z, v.w + bq.w};
  } else if (quad == 1) {
    float4 bq = *(const float4*)(b + 4);
    float* o = out + (size_t)row * NCLS + 4;
    *(float2*)o       = {v.x + bq.x, v.y + bq.y};
    *(float2*)(o + 2) = {v.z + bq.z, v.w + bq.w};
  } else if (quad == 2) {
    *(float2*)(out + (size_t)row * NCLS + 8) = {v.x + b[8], v.y + b[9]};
  }
}

// ---- launch --------------------------------------------------------------

extern "C" void kernel_launch(void* const* d_in, const int* in_sizes, int n_in,
                              void* d_out, int out_size, void* d_ws, size_t ws_size,
                              hipStream_t stream) {
  const float* batches = (const float*)d_in[0];  // [16384,512]
  const float* centers = (const float*)d_in[1];  // [2048,512]
  const float* beta    = (const float*)d_in[2];  // [1,2048]
  const float* W       = (const float*)d_in[3];  // [10,2048]
  const float* bias    = (const float*)d_in[4];  // [10]
  float* out = (float*)d_out;                    // [16384,10]

  char* ws = (char*)d_ws;
  u16*  Abf = (u16*)ws;                                   // 16 MiB
  u16*  Bbf = (u16*)(ws + (size_t)M_N * DIM * 2);         // 2 MiB
  float* x2 = (float*)(ws + (size_t)(M_N + K_C) * DIM * 2);
  float* c2 = x2 + M_N;
  u16*  Wpm = (u16*)(c2 + K_C);                           // 64 KiB
  float* partial = (float*)((char*)Wpm + 16 * K_C * 2);   // 16.8 MiB

  prep<<<dim3(NPREP + 32), dim3(256), 0, stream>>>(
      (const float4*)batches, (const float4*)centers, W,
      (ushort4*)Abf, (ushort4*)Bbf, x2, c2, Wpm);
  rbf_main<<<dim3(8 * (M_N / BM)), dim3(256), 0, stream>>>(
      Abf, Bbf, x2, c2, beta, Wpm, partial);
  reduce_out<<<dim3(M_N / 64), dim3(256), 0, stream>>>(partial, bias, out);
}

// Round 12
// 137.323 us; speedup vs baseline: 1.1810x; 1.1810x over previous
//
#include <hip/hip_runtime.h>
#include <hip/hip_bf16.h>
#include <stdint.h>

// Problem constants (fixed by setup_inputs)
#define M_N  16384   // batch rows
#define K_C  2048    // centers
#define DIM  512     // feature dim
#define NCLS 10      // classes
#define NBN  16      // center-blocks (K_C/128) = partial slices
#define NBM  (M_N / 128)
#define BK   32      // K-chunk (double-buffered)

typedef unsigned short u16;
typedef float  f32x4  __attribute__((ext_vector_type(4)));
typedef __bf16 bf16x8 __attribute__((ext_vector_type(8)));

// ---- helpers -------------------------------------------------------------

__device__ __forceinline__ void async_ld16(const void* g, void* l) {
  // global -> LDS direct DMA, 16 B/lane; LDS dest must be linear in tid,
  // so the XOR swizzle is applied on the global SOURCE address.
  __builtin_amdgcn_global_load_lds(
      (const __attribute__((address_space(1))) void*)g,
      (__attribute__((address_space(3))) void*)l,
      16, 0, 0);
}

__device__ __forceinline__ u16 f2bf_rne(float f) {
  uint32_t u = __float_as_uint(f);
  u += 0x7FFFu + ((u >> 16) & 1u);
  return (u16)(u >> 16);
}

// ---- kernel 1: prep ------------------------------------------------------
// blocks [0, NPREP): 4 rows/block, one wave per row (coalesced i*64+lane).
// last 32 blocks: W fp32 [10][2048] -> PERMUTED bf16 [16][2048] matching
// stage-2 register order (bn 128-chunk, half h, t, q, j).

#define NPREP ((M_N + K_C) / 4)   // 4608

__global__ __launch_bounds__(256) void prep(
    const float4* __restrict__ batches, const float4* __restrict__ centers,
    const float* __restrict__ W,
    ushort4* __restrict__ Abf, ushort4* __restrict__ Bbf,
    float* __restrict__ x2, float* __restrict__ c2, u16* __restrict__ Wperm) {
  int b = blockIdx.x, t = threadIdx.x;
  if (b < NPREP) {
    int lane = t & 63;
    int rp = b * 4 + (t >> 6);          // one wave per row
    const float4* src; ushort4* dst; float* sq; int row;
    if (rp < M_N) { src = batches; dst = Abf; sq = x2; row = rp; }
    else          { src = centers; dst = Bbf; sq = c2; row = rp - M_N; }
    float ss = 0.f;
#pragma unroll
    for (int i = 0; i < 2; ++i) {
      float4 v = src[(size_t)row * 128 + i * 64 + lane];
      ss += v.x * v.x + v.y * v.y + v.z * v.z + v.w * v.w;
      ushort4 o;
      o.x = f2bf_rne(v.x); o.y = f2bf_rne(v.y);
      o.z = f2bf_rne(v.z); o.w = f2bf_rne(v.w);
      dst[(size_t)row * 128 + i * 64 + lane] = o;
    }
    ss += __shfl_down(ss, 32);
    ss += __shfl_down(ss, 16);
    ss += __shfl_down(ss, 8);
    ss += __shfl_down(ss, 4);
    ss += __shfl_down(ss, 2);
    ss += __shfl_down(ss, 1);
    if (lane == 0) sq[row] = ss;
  } else {
    int wb = b - NPREP;                 // 32 blocks x 1024 elems
#pragma unroll
    for (int i = 0; i < 4; ++i) {
      int p = wb * 1024 + i * 256 + t;  // < 16*2048
      int cls = p >> 11, k = p & 2047;
      int bn = k >> 7, rem = k & 127;
      int h = (rem >> 6) & 1, rem2 = rem & 63;
      int tt = rem2 >> 5, qq = (rem2 >> 3) & 3, jj = rem2 & 7;
      int c = bn * 128 + h * 64 + (2 * tt + (jj >> 2)) * 16 + qq * 4 + (jj & 3);
      Wperm[p] = (cls < NCLS) ? f2bf_rne(W[cls * K_C + c]) : (u16)0;
    }
  }
}

// ---- kernel 2: fused xc-GEMM -> radial -> MFMA (radial@Wperm^T) ----------
// grid = 2048 (XCD-swizzled), 256 thr = 4 waves (2x2 of 64x64).
// BK=32 DOUBLE-BUFFERED staging (2 x 16 KB = 32 KB LDS), ONE barrier/iter:
// the barrier drains a DMA issued a full iteration earlier (latency hidden),
// unlike the R10 2-barrier loop that stalled all waves on fresh DMA.
// LDS swizzle: row slot = q ^ ((row>>1)&3) -> 8-lane b128 phases hit 8
// distinct bank-quads (conflict-free at 64 B row size).
// Stage-2 = register-direct MFMA vs Wperm; wave pairs sum via dead LDS.

__global__ __launch_bounds__(256, 4) void rbf_main(
    const u16* __restrict__ A,      // bf16 bits [M_N][DIM]  (batches)
    const u16* __restrict__ B,      // bf16 bits [K_C][DIM]  (centers)
    const float* __restrict__ x2,   // [M_N]
    const float* __restrict__ c2,   // [K_C]
    const float* __restrict__ beta, // [K_C]
    const u16* __restrict__ Wperm,  // bf16 bits [16][K_C] permuted
    float* __restrict__ partial) {  // [NBN][M_N][16]
  __shared__ alignas(16) u16 As[2][128 * BK];   // batches, 2 x 8 KB
  __shared__ alignas(16) u16 Bs[2][128 * BK];   // centers, 2 x 8 KB

  const int tid  = threadIdx.x;
  const int lane = tid & 63;
  const int wid  = tid >> 6;
  const int bid = blockIdx.x;
  const int g = bid >> 3, r8 = bid & 7;
  const int bm = r8 * 16 + (g & 15);
  const int bn = g >> 4;
  const int row0 = bm * 128, col0 = bn * 128;
  const int wrC = (wid >> 1) * 64;   // wave CENTER half
  const int wcB = (wid & 1) * 64;    // wave BATCH half
  const int cls = lane & 15, q = lane >> 4;

  f32x4 acc[4][4] = {};   // [mi centers][ni batches]

  // DMA: thread t -> LDS row t>>2, slot t&3; source chunk (t&3)^((t>>3)&3)
  const int srow = tid >> 2;
  const int schunk = (tid & 3) ^ ((tid >> 3) & 3);
  const u16* aG = A + (size_t)(row0 + srow) * DIM + schunk * 8;
  const u16* bG = B + (size_t)(col0 + srow) * DIM + schunk * 8;

#define FILL(buf, k0)                                          \
  {                                                            \
    async_ld16(aG + (k0),            &As[buf][0]    + tid * 8);\
    async_ld16(aG + (k0) + 64 * DIM, &As[buf][2048] + tid * 8);\
    async_ld16(bG + (k0),            &Bs[buf][0]    + tid * 8);\
    async_ld16(bG + (k0) + 64 * DIM, &Bs[buf][2048] + tid * 8);\
  }

  // fragment LDS offsets (u16): row rr, slot = q ^ ((rr>>1)&3)
  int offC[4], offB[4];
#pragma unroll
  for (int i = 0; i < 4; ++i) {
    int rrC = wrC + i * 16 + cls;
    offC[i] = rrC * BK + (q ^ ((rrC >> 1) & 3)) * 8;
    int rrB = wcB + i * 16 + cls;
    offB[i] = rrB * BK + (q ^ ((rrB >> 1) & 3)) * 8;
  }

  FILL(0, 0)
  for (int it = 0; it < 16; ++it) {
    __syncthreads();                 // drains prev-iter DMA + prev ds_reads
    if (it < 15) FILL((it + 1) & 1, (it + 1) * BK)
    const u16* as_ = As[it & 1];
    const u16* bs_ = Bs[it & 1];
    bf16x8 cf[4], bfr[4];
#pragma unroll
    for (int mi = 0; mi < 4; ++mi)   // centers = FIRST operand
      cf[mi] = *(const bf16x8*)(bs_ + offC[mi]);
#pragma unroll
    for (int ni = 0; ni < 4; ++ni)   // batches = SECOND operand
      bfr[ni] = *(const bf16x8*)(as_ + offB[ni]);
#pragma unroll
    for (int mi = 0; mi < 4; ++mi)
#pragma unroll
      for (int ni = 0; ni < 4; ++ni)
        acc[mi][ni] = __builtin_amdgcn_mfma_f32_16x16x32_bf16(
            cf[mi], bfr[ni], acc[mi][ni], 0, 0, 0);
  }

  // ---- epilogue: acc (xc) -> radial, in place ----
  // D layout: col(lane&15)=batch within ni-strip, row(q*4+r)=center.
  float x2v[4];
#pragma unroll
  for (int ni = 0; ni < 4; ++ni)
    x2v[ni] = x2[row0 + wcB + ni * 16 + cls];
#pragma unroll
  for (int mi = 0; mi < 4; ++mi) {
    int base = col0 + wrC + mi * 16 + q * 4;
    float4 cq = *(const float4*)(c2 + base);
    float4 bq = *(const float4*)(beta + base);
#pragma unroll
    for (int ni = 0; ni < 4; ++ni)
#pragma unroll
      for (int r = 0; r < 4; ++r) {
        float xc = acc[mi][ni][r];
        float d2 = fmaxf(x2v[ni] + cq[r] - 2.0f * xc, 0.0f);
        acc[mi][ni][r] = __expf(-bq[r] * sqrtf(d2));
      }
  }

  // ---- stage 2: acc2[64 x 16cls] = radial(64 centers) @ Wperm^T ----
  // Wperm order: k=q*8+j <-> center (2t+(j>>2))*16 + q*4 + (j&3), half h.
  const int h = wid >> 1;
  f32x4 acc2[4] = {};
#pragma unroll
  for (int t = 0; t < 2; ++t) {
    bf16x8 wfr = *(const bf16x8*)(Wperm + (size_t)cls * K_C + col0 +
                                  h * 64 + t * 32 + q * 8);
#pragma unroll
    for (int ni = 0; ni < 4; ++ni) {
      bf16x8 pk;
#pragma unroll
      for (int r = 0; r < 4; ++r) {
        pk[r]     = (__bf16)acc[2 * t][ni][r];      // HW v_cvt (RNE)
        pk[4 + r] = (__bf16)acc[2 * t + 1][ni][r];
      }
      acc2[ni] = __builtin_amdgcn_mfma_f32_16x16x32_bf16(
          pk, wfr, acc2[ni], 0, 0, 0);
    }
  }

  // ---- wave-pair sum (waves h=0,1 share batches) via dead staging LDS ----
  f32x4* sumbuf = (f32x4*)As;
  __syncthreads();   // all K-loop ds_reads done; staging reusable
  if (wid >= 2) {
#pragma unroll
    for (int ni = 0; ni < 4; ++ni)
      sumbuf[((wid - 2) * 4 + ni) * 64 + lane] = acc2[ni];
  }
  __syncthreads();
  if (wid < 2) {
#pragma unroll
    for (int ni = 0; ni < 4; ++ni) {
      acc2[ni] += sumbuf[(wid * 4 + ni) * 64 + lane];
      // D2: col(lane&15)=class, row(q*4+r)=batch row within strip.
#pragma unroll
      for (int r = 0; r < 4; ++r) {
        int gr = row0 + wid * 64 + ni * 16 + q * 4 + r;
        partial[((size_t)bn * M_N + gr) * 16 + cls] = acc2[ni][r];
      }
    }
  }
}

// ---- kernel 3: out[i][:] = b + sum_s partial[s][i][:] --------------------
// 4 threads per row (float4 quads); 1 KB contiguous per wave per slice.

__global__ __launch_bounds__(256) void reduce_out(
    const float* __restrict__ partial, const float* __restrict__ b,
    float* __restrict__ out) {
  int t = threadIdx.x;
  int row = blockIdx.x * 64 + (t >> 2);
  int quad = t & 3;
  f32x4 v = {0.f, 0.f, 0.f, 0.f};
#pragma unroll
  for (int s = 0; s < NBN; ++s) {
    f32x4 p = __builtin_nontemporal_load(
        (const f32x4*)(partial + ((size_t)s * M_N + row) * 16 + quad * 4));
    v += p;
  }
  if (quad == 0) {
    float4 bq = *(const float4*)b;
    float* o = out + (size_t)row * NCLS;
    *(float2*)o       = {v.x + bq.x, v.y + bq.y};
    *(float2*)(o + 2) = {v.z + bq.z, v.w + bq.w};
  } else if (quad == 1) {
    float4 bq = *(const float4*)(b + 4);
    float* o = out + (size_t)row * NCLS + 4;
    *(float2*)o       = {v.x + bq.x, v.y + bq.y};
    *(float2*)(o + 2) = {v.z + bq.z, v.w + bq.w};
  } else if (quad == 2) {
    *(float2*)(out + (size_t)row * NCLS + 8) = {v.x + b[8], v.y + b[9]};
  }
}

// ---- launch --------------------------------------------------------------

extern "C" void kernel_launch(void* const* d_in, const int* in_sizes, int n_in,
                              void* d_out, int out_size, void* d_ws, size_t ws_size,
                              hipStream_t stream) {
  const float* batches = (const float*)d_in[0];  // [16384,512]
  const float* centers = (const float*)d_in[1];  // [2048,512]
  const float* beta    = (const float*)d_in[2];  // [1,2048]
  const float* W       = (const float*)d_in[3];  // [10,2048]
  const float* bias    = (const float*)d_in[4];  // [10]
  float* out = (float*)d_out;                    // [16384,10]

  char* ws = (char*)d_ws;
  u16*  Abf = (u16*)ws;                                   // 16 MiB
  u16*  Bbf = (u16*)(ws + (size_t)M_N * DIM * 2);         // 2 MiB
  float* x2 = (float*)(ws + (size_t)(M_N + K_C) * DIM * 2);
  float* c2 = x2 + M_N;
  u16*  Wpm = (u16*)(c2 + K_C);                           // 64 KiB
  float* partial = (float*)((char*)Wpm + 16 * K_C * 2);   // 16.8 MiB

  prep<<<dim3(NPREP + 32), dim3(256), 0, stream>>>(
      (const float4*)batches, (const float4*)centers, W,
      (ushort4*)Abf, (ushort4*)Bbf, x2, c2, Wpm);
  rbf_main<<<dim3(NBN * NBM), dim3(256), 0, stream>>>(
      Abf, Bbf, x2, c2, beta, Wpm, partial);
  reduce_out<<<dim3(M_N / 64), dim3(256), 0, stream>>>(partial, bias, out);
}